// Round 18
// baseline (469.637 us; speedup 1.0000x reference)
//
#include <hip/hip_runtime.h>

#define NN 100000
#define NE 1600000
#define DIM 128
#define NA 5
#define STEPS 5

// single-u64 coeff packing: 4 x 14-bit slots (scale 2^7) + 7-bit count@56.
// c4 reconstructed via softmax sum-to-1: c4 = count - (c0+c1+c2+c3).
#define CSCALE3 128.0f
#define CINV3   0.0078125f  // 2^-7

typedef float f32x4 __attribute__((ext_vector_type(4)));
typedef short short8v __attribute__((ext_vector_type(8)));
typedef unsigned u32x4 __attribute__((ext_vector_type(4)));

__device__ __forceinline__ float wsum(float v) {
#pragma unroll
  for (int off = 32; off > 0; off >>= 1) v += __shfl_xor(v, off, 64);
  return v;
}

// pack two f32 into one u32 of 2 bf16 (truncation): low16 = bf16(a), high16 = bf16(b)
__device__ __forceinline__ unsigned pkhi(float a, float b) {
  return __builtin_amdgcn_perm(__float_as_uint(b), __float_as_uint(a),
                               0x07060302u);
}
// residual after bf16 truncation (exact: hi+lo == x)
__device__ __forceinline__ float lof(float x) {
  return x - __uint_as_float(__float_as_uint(x) & 0xffff0000u);
}
// unpack a pkhi word
__device__ __forceinline__ float upk0(unsigned u) {
  return __uint_as_float(u << 16);
}
__device__ __forceinline__ float upk1(unsigned u) {
  return __uint_as_float(u & 0xffff0000u);
}

// ---- prep: M = edge_anchor @ W1b.T ----
__global__ __launch_bounds__(128) void k_prepM(
    const float* __restrict__ W1, const float* __restrict__ edge_anchor,
    float* __restrict__ M) {
  const int i = threadIdx.x;
  const int a = blockIdx.x;
  float s = 0.f;
  for (int j = 0; j < DIM; ++j)
    s = fmaf(edge_anchor[a * DIM + j], W1[i * 2 * DIM + DIM + j], s);
  M[a * DIM + i] = s;
}

// ---- pack W1 (A-frags, native) and W2 (A-frags with sigma/tau permutation)
// layout: wp[((mat*2+part)*32 + nf*4+ks)*64 + lane], 16B each (8 bf16)
__global__ __launch_bounds__(256) void k_wpack(
    const float* __restrict__ W1, const float* __restrict__ W2,
    uint4* __restrict__ wp) {
  const int mat = blockIdx.x >> 3, nf = blockIdx.x & 7;
  const int ks = threadIdx.x >> 6, lane = threadIdx.x & 63;
  const int g = lane >> 4, r = lane & 15;
  float v[8];
  if (mat == 0) {
    const float* src = W1 + (16 * nf + r) * 256 + 32 * ks + 8 * g;
    float4 a = *(const float4*)src;
    float4 b = *(const float4*)(src + 4);
    v[0] = a.x; v[1] = a.y; v[2] = a.z; v[3] = a.w;
    v[4] = b.x; v[5] = b.y; v[6] = b.z; v[7] = b.w;
  } else {
    // tau = 32*(nf>>1) + 8*(r>>2) + 4*(nf&1) + (r&3)
    // sigma = 32ks + 16*(j>>2) + 4g + (j&3)
    const int trow = 32 * (nf >> 1) + 8 * (r >> 2) + 4 * (nf & 1) + (r & 3);
    const float* src = W2 + trow * 128 + 32 * ks + 4 * g;
    float4 a = *(const float4*)src;         // j=0..3
    float4 b = *(const float4*)(src + 16);  // j=4..7
    v[0] = a.x; v[1] = a.y; v[2] = a.z; v[3] = a.w;
    v[4] = b.x; v[5] = b.y; v[6] = b.z; v[7] = b.w;
  }
  unsigned h[4], l[4];
#pragma unroll
  for (int w = 0; w < 4; ++w) {
    h[w] = pkhi(v[2 * w], v[2 * w + 1]);
    l[w] = pkhi(lof(v[2 * w]), lof(v[2 * w + 1]));
  }
  wp[((mat * 2 + 0) * 32 + nf * 4 + ks) * 64 + lane] =
      make_uint4(h[0], h[1], h[2], h[3]);
  wp[((mat * 2 + 1) * 32 + nf * 4 + ks) * 64 + lane] =
      make_uint4(l[0], l[1], l[2], l[3]);
}

// ---- node pre-pass: att softmax + node_x, and p1/p2 edge projections ----
__global__ __launch_bounds__(256) void k_node(
    const float* __restrict__ x, const float* __restrict__ W_att,
    const float* __restrict__ b_att, const float* __restrict__ node_anchor,
    const float* __restrict__ W_edge, const float* __restrict__ b_edge,
    float* __restrict__ node_x, float* __restrict__ p12) {
  const int wid = threadIdx.x >> 6, lane = threadIdx.x & 63;
  const int d0 = lane << 1;
  float wa0[NA], wa1[NA], we10[NA], we11[NA], we20[NA], we21[NA];
  float na0[NA], na1[NA], ba[NA], be[NA];
#pragma unroll
  for (int a = 0; a < NA; ++a) {
    wa0[a] = W_att[a * DIM + d0];
    wa1[a] = W_att[a * DIM + d0 + 1];
    we10[a] = W_edge[a * 2 * DIM + d0];
    we11[a] = W_edge[a * 2 * DIM + d0 + 1];
    we20[a] = W_edge[a * 2 * DIM + DIM + d0];
    we21[a] = W_edge[a * 2 * DIM + DIM + d0 + 1];
    na0[a] = node_anchor[a * DIM + d0];
    na1[a] = node_anchor[a * DIM + d0 + 1];
    ba[a] = b_att[a];
    be[a] = b_edge[a];
  }
  const int stride = gridDim.x << 2;
  for (int n = (blockIdx.x << 2) + wid; n < NN; n += stride) {
    float2 xv = *(const float2*)(x + (size_t)n * DIM + d0);
    float att[NA], p1[NA], p2[NA];
#pragma unroll
    for (int a = 0; a < NA; ++a) {
      att[a] = wsum(xv.x * wa0[a] + xv.y * wa1[a]) + ba[a];
      p1[a] = wsum(xv.x * we10[a] + xv.y * we11[a]) + be[a];
      p2[a] = wsum(xv.x * we20[a] + xv.y * we21[a]);
    }
    float m = fmaxf(fmaxf(fmaxf(att[0], att[1]), fmaxf(att[2], att[3])), att[4]);
    float s = 0.f;
#pragma unroll
    for (int a = 0; a < NA; ++a) { att[a] = expf(att[a] - m); s += att[a]; }
    float inv = 1.f / s;
    float2 nx = xv;
#pragma unroll
    for (int a = 0; a < NA; ++a) {
      float w = att[a] * inv;
      nx.x = fmaf(w, na0[a], nx.x);
      nx.y = fmaf(w, na1[a], nx.y);
    }
    *(float2*)(node_x + (size_t)n * DIM + d0) = nx;
    if (lane < NA) {
      float v1 = p1[0], v2 = p2[0];
#pragma unroll
      for (int a = 1; a < NA; ++a)
        if (lane == a) { v1 = p1[a]; v2 = p2[a]; }
      p12[(size_t)n * 12 + lane] = v1;
      p12[(size_t)n * 12 + 6 + lane] = v2;
    }
  }
}

__device__ __forceinline__ void edge_b(const float* __restrict__ p12, int src,
                                       int dst, float* __restrict__ b) {
  float4 q1 = *(const float4*)(p12 + (size_t)src * 12);
  float p14 = p12[(size_t)src * 12 + 4];
  float2 r0 = *(const float2*)(p12 + (size_t)dst * 12 + 6);
  float2 r1 = *(const float2*)(p12 + (size_t)dst * 12 + 8);
  float p24 = p12[(size_t)dst * 12 + 10];
  float l[NA] = {q1.x + r0.x, q1.y + r0.y, q1.z + r1.x, q1.w + r1.y,
                 p14 + p24};
#pragma unroll
  for (int a = 0; a < NA; ++a) l[a] = l[a] >= 0.f ? l[a] : 0.01f * l[a];
  float m = fmaxf(fmaxf(fmaxf(l[0], l[1]), fmaxf(l[2], l[3])), l[4]);
  float s = 0.f;
#pragma unroll
  for (int a = 0; a < NA; ++a) { l[a] = expf(l[a] - m); s += l[a]; }
  float inv = 1.f / s;
#pragma unroll
  for (int a = 0; a < NA; ++a) b[a] = l[a] * inv;
}

// ---- fused edge pass: ep NT-store stream with the 2 coeff atomics issued
// MID-LOOP (between store iterations 15/16) so the store stream surrounds the
// atomics in the VMEM queue — tests atomic/store overlap.
__global__ __launch_bounds__(256) void k_edge2(
    const int* __restrict__ ei, const float* __restrict__ p12,
    const float* __restrict__ edge_anchor,
    unsigned long long* __restrict__ coeffp, float* __restrict__ ep) {
  __shared__ float bs[4][64][8];
  const int t = threadIdx.x;
  const int w = t >> 6, lane = t & 63;
  const int e = blockIdx.x * 256 + t;
  const int src = ei[e], dst = ei[NE + e];
  unsigned long long wv;
  {
    float b[NA];
    edge_b(p12, src, dst, b);
    // 4 x 14-bit slots (scale 2^7, q<=128, deg<=127 => sum<16384) + count@56
    unsigned long long q0 = (unsigned)fmaf(b[0], CSCALE3, 0.5f);
    unsigned long long q1 = (unsigned)fmaf(b[1], CSCALE3, 0.5f);
    unsigned long long q2 = (unsigned)fmaf(b[2], CSCALE3, 0.5f);
    unsigned long long q3 = (unsigned)fmaf(b[3], CSCALE3, 0.5f);
    wv = q0 | (q1 << 14) | (q2 << 28) | (q3 << 42) | (1ull << 56);
    // wave-private LDS slice: same-wave DS ops are in-order, no barrier
    *(float4*)&bs[w][lane][0] = make_float4(b[0], b[1], b[2], b[3]);
    bs[w][lane][4] = b[4];
  }
  // 2 edges per iter, float4 NT stores
  const int esub = lane >> 5, d0 = (lane & 31) << 2;
  float4 ea4[NA];
#pragma unroll
  for (int a = 0; a < NA; ++a)
    ea4[a] = *(const float4*)(edge_anchor + a * DIM + d0);
  const size_t ebase = (size_t)blockIdx.x * 256 + ((size_t)w << 6);
#pragma unroll 2
  for (int k = 0; k < 16; ++k) {
    const int el = 2 * k + esub;
    float4 c = *(const float4*)&bs[w][el][0];
    float c4 = bs[w][el][4];
    f32x4 v;
#pragma unroll
    for (int i = 0; i < 4; ++i) {
      float s = c.x * ((const float*)&ea4[0])[i];
      s = fmaf(c.y, ((const float*)&ea4[1])[i], s);
      s = fmaf(c.z, ((const float*)&ea4[2])[i], s);
      s = fmaf(c.w, ((const float*)&ea4[3])[i], s);
      s = fmaf(c4, ((const float*)&ea4[4])[i], s);
      v[i] = s;
    }
    __builtin_nontemporal_store(v, (f32x4*)(ep + (ebase + el) * DIM + d0));
  }
  atomicAdd(coeffp + src, wv);
  atomicAdd(coeffp + dst, wv);
#pragma unroll 2
  for (int k = 16; k < 32; ++k) {
    const int el = 2 * k + esub;
    float4 c = *(const float4*)&bs[w][el][0];
    float c4 = bs[w][el][4];
    f32x4 v;
#pragma unroll
    for (int i = 0; i < 4; ++i) {
      float s = c.x * ((const float*)&ea4[0])[i];
      s = fmaf(c.y, ((const float*)&ea4[1])[i], s);
      s = fmaf(c.z, ((const float*)&ea4[2])[i], s);
      s = fmaf(c.w, ((const float*)&ea4[3])[i], s);
      s = fmaf(c4, ((const float*)&ea4[4])[i], s);
      v[i] = s;
    }
    __builtin_nontemporal_store(v, (f32x4*)(ep + (ebase + el) * DIM + d0));
  }
}

// ---- ODE: all 5 steps in ONE launch (fenced seams, r16/r17-proven), now at
// 1024 threads/block (16 waves/CU vs 8) — VGPR=128 fits 4 waves/SIMD, so
// doubling resident waves doubles latency hiding for the MFMA/DS chains.
#define WF(MAT, PART, IDX) (*(const short8v*)&wl[MAT][PART][IDX][lane])

#define MFMA3(WH, WO, BH, BL, ACC)                                            \
  ACC = __builtin_amdgcn_mfma_f32_16x16x32_bf16(                              \
      WH, __builtin_bit_cast(short8v, BH), ACC, 0, 0, 0);                     \
  ACC = __builtin_amdgcn_mfma_f32_16x16x32_bf16(                              \
      WH, __builtin_bit_cast(short8v, BL), ACC, 0, 0, 0);                     \
  ACC = __builtin_amdgcn_mfma_f32_16x16x32_bf16(                              \
      WO, __builtin_bit_cast(short8v, BH), ACC, 0, 0, 0);

#define LOADKS(KS, BH, BL)                                                    \
  {                                                                           \
    float4 a = make_float4(0.f, 0.f, 0.f, 0.f), b = a;                        \
    if (ok) {                                                                 \
      const float* p = ev + (size_t)node * DIM + 32 * KS + 8 * g;             \
      a = *(const float4*)p;                                                  \
      b = *(const float4*)(p + 4);                                            \
    }                                                                         \
    BH[0] = pkhi(a.x, a.y); BL[0] = pkhi(lof(a.x), lof(a.y));                 \
    BH[1] = pkhi(a.z, a.w); BL[1] = pkhi(lof(a.z), lof(a.w));                 \
    BH[2] = pkhi(b.x, b.y); BL[2] = pkhi(lof(b.x), lof(b.y));                 \
    BH[3] = pkhi(b.z, b.w); BL[3] = pkhi(lof(b.z), lof(b.w));                 \
  }

// mv1 for one nf: transient aggp init (LDS Ms/b1s), 12 MFMAs in 2 chains,
// relu, pack into Qh/Ql words (compile-time slots).
#define MV1NF(NF, QH, QL, W0)                                                 \
  {                                                                           \
    float4 bb = *(const float4*)&b1s[16 * NF + 4 * g];                        \
    f32x4 acc = {bb.x, bb.y, bb.z, bb.w};                                     \
    {                                                                         \
      float4 mm = *(const float4*)&Ms[0][16 * NF + 4 * g];                    \
      acc[0] = fmaf(c0, mm.x, acc[0]); acc[1] = fmaf(c0, mm.y, acc[1]);       \
      acc[2] = fmaf(c0, mm.z, acc[2]); acc[3] = fmaf(c0, mm.w, acc[3]);       \
    }                                                                         \
    {                                                                         \
      float4 mm = *(const float4*)&Ms[1][16 * NF + 4 * g];                    \
      acc[0] = fmaf(c1, mm.x, acc[0]); acc[1] = fmaf(c1, mm.y, acc[1]);       \
      acc[2] = fmaf(c1, mm.z, acc[2]); acc[3] = fmaf(c1, mm.w, acc[3]);       \
    }                                                                         \
    {                                                                         \
      float4 mm = *(const float4*)&Ms[2][16 * NF + 4 * g];                    \
      acc[0] = fmaf(c2, mm.x, acc[0]); acc[1] = fmaf(c2, mm.y, acc[1]);       \
      acc[2] = fmaf(c2, mm.z, acc[2]); acc[3] = fmaf(c2, mm.w, acc[3]);       \
    }                                                                         \
    {                                                                         \
      float4 mm = *(const float4*)&Ms[3][16 * NF + 4 * g];                    \
      acc[0] = fmaf(c3, mm.x, acc[0]); acc[1] = fmaf(c3, mm.y, acc[1]);       \
      acc[2] = fmaf(c3, mm.z, acc[2]); acc[3] = fmaf(c3, mm.w, acc[3]);       \
    }                                                                         \
    {                                                                         \
      float4 mm = *(const float4*)&Ms[4][16 * NF + 4 * g];                    \
      acc[0] = fmaf(c4, mm.x, acc[0]); acc[1] = fmaf(c4, mm.y, acc[1]);       \
      acc[2] = fmaf(c4, mm.z, acc[2]); acc[3] = fmaf(c4, mm.w, acc[3]);       \
    }                                                                         \
    f32x4 accB = {0.f, 0.f, 0.f, 0.f};                                        \
    { short8v wh = WF(0, 0, NF * 4 + 0), wo = WF(0, 1, NF * 4 + 0);           \
      MFMA3(wh, wo, Bh0, Bl0, acc) }                                          \
    { short8v wh = WF(0, 0, NF * 4 + 1), wo = WF(0, 1, NF * 4 + 1);           \
      MFMA3(wh, wo, Bh1, Bl1, accB) }                                         \
    { short8v wh = WF(0, 0, NF * 4 + 2), wo = WF(0, 1, NF * 4 + 2);           \
      MFMA3(wh, wo, Bh2, Bl2, acc) }                                          \
    { short8v wh = WF(0, 0, NF * 4 + 3), wo = WF(0, 1, NF * 4 + 3);           \
      MFMA3(wh, wo, Bh3, Bl3, accB) }                                         \
    float h0 = fmaxf(acc[0] + accB[0], 0.f);                                  \
    float h1 = fmaxf(acc[1] + accB[1], 0.f);                                  \
    float h2 = fmaxf(acc[2] + accB[2], 0.f);                                  \
    float h3 = fmaxf(acc[3] + accB[3], 0.f);                                  \
    QH[W0] = pkhi(h0, h1);                                                    \
    QH[W0 + 1] = pkhi(h2, h3);                                                \
    QL[W0] = pkhi(lof(h0), lof(h1));                                          \
    QL[W0 + 1] = pkhi(lof(h2), lof(h3));                                      \
  }

// mv2 24-MFMA core for one kq (nf=2kq and 2kq+1), 2 chains each
#define MV2CORE(KQ)                                                           \
  f32x4 a2a = {0.f, 0.f, 0.f, 0.f}, a2aB = a2a;                               \
  { short8v wh = WF(1, 0, (2 * KQ) * 4 + 0), wo = WF(1, 1, (2 * KQ) * 4 + 0); \
    MFMA3(wh, wo, Qh0, Ql0, a2a) }                                            \
  { short8v wh = WF(1, 0, (2 * KQ) * 4 + 1), wo = WF(1, 1, (2 * KQ) * 4 + 1); \
    MFMA3(wh, wo, Qh1, Ql1, a2aB) }                                           \
  { short8v wh = WF(1, 0, (2 * KQ) * 4 + 2), wo = WF(1, 1, (2 * KQ) * 4 + 2); \
    MFMA3(wh, wo, Qh2, Ql2, a2a) }                                            \
  { short8v wh = WF(1, 0, (2 * KQ) * 4 + 3), wo = WF(1, 1, (2 * KQ) * 4 + 3); \
    MFMA3(wh, wo, Qh3, Ql3, a2aB) }                                           \
  f32x4 a2b = {0.f, 0.f, 0.f, 0.f}, a2bB = a2b;                               \
  { short8v wh = WF(1, 0, (2 * KQ + 1) * 4 + 0), wo = WF(1, 1, (2 * KQ + 1) * 4 + 0); \
    MFMA3(wh, wo, Qh0, Ql0, a2b) }                                            \
  { short8v wh = WF(1, 0, (2 * KQ + 1) * 4 + 1), wo = WF(1, 1, (2 * KQ + 1) * 4 + 1); \
    MFMA3(wh, wo, Qh1, Ql1, a2bB) }                                           \
  { short8v wh = WF(1, 0, (2 * KQ + 1) * 4 + 2), wo = WF(1, 1, (2 * KQ + 1) * 4 + 2); \
    MFMA3(wh, wo, Qh2, Ql2, a2b) }                                            \
  { short8v wh = WF(1, 0, (2 * KQ + 1) * 4 + 3), wo = WF(1, 1, (2 * KQ + 1) * 4 + 3); \
    MFMA3(wh, wo, Qh3, Ql3, a2bB) }

// mv2 + store to ev (final step)
#define MV2KQ(KQ, BH, BL)                                                     \
  {                                                                           \
    MV2CORE(KQ)                                                               \
    if (ok) {                                                                 \
      float4 bv0 = *(const float4*)&b2s[32 * KQ + 8 * g];                     \
      float4 bv1 = *(const float4*)&b2s[32 * KQ + 8 * g + 4];                 \
      float4 o0, o1;                                                          \
      o0.x = upk0(BH[0]) + upk0(BL[0]) + fmaf(dt, a2a[0] + a2aB[0], bv0.x);   \
      o0.y = upk1(BH[0]) + upk1(BL[0]) + fmaf(dt, a2a[1] + a2aB[1], bv0.y);   \
      o0.z = upk0(BH[1]) + upk0(BL[1]) + fmaf(dt, a2a[2] + a2aB[2], bv0.z);   \
      o0.w = upk1(BH[1]) + upk1(BL[1]) + fmaf(dt, a2a[3] + a2aB[3], bv0.w);   \
      o1.x = upk0(BH[2]) + upk0(BL[2]) + fmaf(dt, a2b[0] + a2bB[0], bv1.x);   \
      o1.y = upk1(BH[2]) + upk1(BL[2]) + fmaf(dt, a2b[1] + a2bB[1], bv1.y);   \
      o1.z = upk0(BH[3]) + upk0(BL[3]) + fmaf(dt, a2b[2] + a2bB[2], bv1.z);   \
      o1.w = upk1(BH[3]) + upk1(BL[3]) + fmaf(dt, a2b[3] + a2bB[3], bv1.w);   \
      float* p = ev + (size_t)node * DIM + 32 * KQ + 8 * g;                   \
      *(float4*)p = o0;                                                       \
      *(float4*)(p + 4) = o1;                                                 \
    }                                                                         \
  }

// mv2 + in-register update of Bh/Bl (intermediate step; hi+lo split is exact,
// so this is bit-identical to store->reload->repack)
#define MV2KQR(KQ, BH, BL)                                                    \
  {                                                                           \
    MV2CORE(KQ)                                                               \
    float4 bv0 = *(const float4*)&b2s[32 * KQ + 8 * g];                       \
    float4 bv1 = *(const float4*)&b2s[32 * KQ + 8 * g + 4];                   \
    float n0 = upk0(BH[0]) + upk0(BL[0]) + fmaf(dt, a2a[0] + a2aB[0], bv0.x); \
    float n1 = upk1(BH[0]) + upk1(BL[0]) + fmaf(dt, a2a[1] + a2aB[1], bv0.y); \
    float n2 = upk0(BH[1]) + upk0(BL[1]) + fmaf(dt, a2a[2] + a2aB[2], bv0.z); \
    float n3 = upk1(BH[1]) + upk1(BL[1]) + fmaf(dt, a2a[3] + a2aB[3], bv0.w); \
    float n4 = upk0(BH[2]) + upk0(BL[2]) + fmaf(dt, a2b[0] + a2bB[0], bv1.x); \
    float n5 = upk1(BH[2]) + upk1(BL[2]) + fmaf(dt, a2b[1] + a2bB[1], bv1.y); \
    float n6 = upk0(BH[3]) + upk0(BL[3]) + fmaf(dt, a2b[2] + a2bB[2], bv1.z); \
    float n7 = upk1(BH[3]) + upk1(BL[3]) + fmaf(dt, a2b[3] + a2bB[3], bv1.w); \
    BH[0] = pkhi(n0, n1); BL[0] = pkhi(lof(n0), lof(n1));                     \
    BH[1] = pkhi(n2, n3); BL[1] = pkhi(lof(n2), lof(n3));                     \
    BH[2] = pkhi(n4, n5); BL[2] = pkhi(lof(n4), lof(n5));                     \
    BH[3] = pkhi(n6, n7); BL[3] = pkhi(lof(n6), lof(n7));                     \
  }

#define MV1_ALL                                                               \
  MV1NF(0, Qh0, Ql0, 0) MV1NF(1, Qh0, Ql0, 2)                                 \
  MV1NF(2, Qh1, Ql1, 0) MV1NF(3, Qh1, Ql1, 2)                                 \
  MV1NF(4, Qh2, Ql2, 0) MV1NF(5, Qh2, Ql2, 2)                                 \
  MV1NF(6, Qh3, Ql3, 0) MV1NF(7, Qh3, Ql3, 2)

// one intermediate ODE step (in-register EV update)
#define STEP_MID                                                              \
  {                                                                           \
    u32x4 Qh0, Qh1, Qh2, Qh3, Ql0, Ql1, Ql2, Ql3;                             \
    MV1_ALL                                                                   \
    MV2KQR(0, Bh0, Bl0)                                                       \
    MV2KQR(1, Bh1, Bl1)                                                       \
    MV2KQR(2, Bh2, Bl2)                                                       \
    MV2KQR(3, Bh3, Bl3)                                                       \
  }

// seam: memory fence + hard scheduling barrier (nothing crosses)
#define SEAM                                                                  \
  __syncthreads();                                                            \
  __builtin_amdgcn_sched_barrier(0);

#define PROLOGUE                                                              \
  __shared__ uint4 wl[2][2][32][64];                                          \
  __shared__ float b2s[DIM];                                                  \
  __shared__ float b1s[DIM];                                                  \
  __shared__ float Ms[NA][DIM];                                               \
  const int tid = threadIdx.x;                                                \
  {                                                                           \
    uint4* dst = &wl[0][0][0][0];                                             \
    _Pragma("unroll")                                                         \
    for (int i = 0; i < 8; ++i) dst[i * 1024 + tid] = wp[i * 1024 + tid];     \
  }                                                                           \
  if (tid < DIM) {                                                            \
    b2s[tid] = (1.f / STEPS) * b2[tid];                                       \
    b1s[tid] = b1[tid];                                                       \
  }                                                                           \
  if (tid >= DIM && tid < DIM + NA * DIM / 4) {                               \
    const int q = tid - DIM;                                                  \
    ((float4*)&Ms[0][0])[q] = ((const float4*)M)[q];                          \
  }                                                                           \
  const int wid = tid >> 6, lane = tid & 63;                                  \
  const int g = lane >> 4, r = lane & 15;                                     \
  const int node = blockIdx.x * 256 + wid * 16 + r;                           \
  const bool ok = node < NN;                                                  \
  const float dt = 1.f / STEPS;                                               \
  u32x4 Bh0, Bh1, Bh2, Bh3, Bl0, Bl1, Bl2, Bl3;                               \
  LOADKS(0, Bh0, Bl0)                                                         \
  LOADKS(1, Bh1, Bl1)                                                         \
  LOADKS(2, Bh2, Bl2)                                                         \
  LOADKS(3, Bh3, Bl3)                                                         \
  float c0 = 0.f, c1 = 0.f, c2 = 0.f, c3 = 0.f, c4 = 0.f;                     \
  if (ok) {                                                                   \
    unsigned long long v = coeffp[node];                                      \
    c0 = (float)(unsigned)(v & 0x3FFFu) * CINV3;                              \
    c1 = (float)(unsigned)((v >> 14) & 0x3FFFu) * CINV3;                      \
    c2 = (float)(unsigned)((v >> 28) & 0x3FFFu) * CINV3;                      \
    c3 = (float)(unsigned)((v >> 42) & 0x3FFFu) * CINV3;                      \
    float cnt = (float)(unsigned)(v >> 56);                                   \
    c4 = cnt - (c0 + c1 + c2 + c3);                                           \
  }                                                                           \
  __syncthreads();

// all 5 ODE steps, 4 fenced seams, 16 waves/block
__global__ __launch_bounds__(1024) void k_step5(
    const unsigned long long* __restrict__ coeffp, const float* __restrict__ M,
    const uint4* __restrict__ wp, const float* __restrict__ b1,
    const float* __restrict__ b2, float* __restrict__ ev) {
  PROLOGUE
  STEP_MID
  SEAM
  STEP_MID
  SEAM
  STEP_MID
  SEAM
  STEP_MID
  SEAM
  {
    u32x4 Qh0, Qh1, Qh2, Qh3, Ql0, Ql1, Ql2, Ql3;
    MV1_ALL
    MV2KQ(0, Bh0, Bl0)
    MV2KQ(1, Bh1, Bl1)
    MV2KQ(2, Bh2, Bl2)
    MV2KQ(3, Bh3, Bl3)
  }
}

extern "C" void kernel_launch(void* const* d_in, const int* in_sizes, int n_in,
                              void* d_out, int out_size, void* d_ws,
                              size_t ws_size, hipStream_t stream) {
  const float* x = (const float*)d_in[0];
  const int* ei = (const int*)d_in[1];
  const float* node_anchor = (const float*)d_in[2];
  const float* W_att = (const float*)d_in[3];
  const float* b_att = (const float*)d_in[4];
  const float* edge_anchor = (const float*)d_in[5];
  const float* W_edge = (const float*)d_in[6];
  const float* b_edge = (const float*)d_in[7];
  const float* W1 = (const float*)d_in[8];
  const float* b1 = (const float*)d_in[9];
  const float* W2 = (const float*)d_in[10];
  const float* b2 = (const float*)d_in[11];

  float* out = (float*)d_out;
  float* ev = out;                     // N*DIM (node_x staged here, then ev)
  float* ep = out + (size_t)NN * DIM;  // E*DIM edge_prompt

  char* ws = (char*)d_ws;
  float* p12 = (float*)(ws);  // N*12 floats = 4.8 MB
  unsigned long long* coeffp =
      (unsigned long long*)(ws + 4800000);   // N u64 = 0.8 MB
  float* Mm = (float*)(ws + 5600000);        // 5*128 floats
  uint4* wpack = (uint4*)(ws + 5602560);     // 128 KB packed W frags

  hipMemsetAsync(coeffp, 0, (size_t)NN * sizeof(unsigned long long), stream);
  k_prepM<<<NA, DIM, 0, stream>>>(W1, edge_anchor, Mm);
  k_wpack<<<16, 256, 0, stream>>>(W1, W2, wpack);
  k_node<<<2048, 256, 0, stream>>>(x, W_att, b_att, node_anchor, W_edge, b_edge,
                                   ev, p12);
  k_edge2<<<NE / 256, 256, 0, stream>>>(ei, p12, edge_anchor, coeffp, ep);
  k_step5<<<(NN + 255) / 256, 1024, 0, stream>>>(coeffp, Mm, wpack, b1, b2, ev);
}

// Round 19
// 419.881 us; speedup vs baseline: 1.1185x; 1.1185x over previous
//
#include <hip/hip_runtime.h>

#define NN 100000
#define NE 1600000
#define DIM 128
#define NA 5
#define STEPS 5

// single-u64 coeff packing: 4 x 14-bit slots (scale 2^7) + 7-bit count@56.
// c4 reconstructed via softmax sum-to-1: c4 = count - (c0+c1+c2+c3).
#define CSCALE3 128.0f
#define CINV3   0.0078125f  // 2^-7

typedef float f32x4 __attribute__((ext_vector_type(4)));
typedef short short8v __attribute__((ext_vector_type(8)));
typedef unsigned u32x4 __attribute__((ext_vector_type(4)));

__device__ __forceinline__ float wsum(float v) {
#pragma unroll
  for (int off = 32; off > 0; off >>= 1) v += __shfl_xor(v, off, 64);
  return v;
}

// pack two f32 into one u32 of 2 bf16 (truncation): low16 = bf16(a), high16 = bf16(b)
__device__ __forceinline__ unsigned pkhi(float a, float b) {
  return __builtin_amdgcn_perm(__float_as_uint(b), __float_as_uint(a),
                               0x07060302u);
}
// residual after bf16 truncation (exact: hi+lo == x)
__device__ __forceinline__ float lof(float x) {
  return x - __uint_as_float(__float_as_uint(x) & 0xffff0000u);
}
// unpack a pkhi word
__device__ __forceinline__ float upk0(unsigned u) {
  return __uint_as_float(u << 16);
}
__device__ __forceinline__ float upk1(unsigned u) {
  return __uint_as_float(u & 0xffff0000u);
}

// ---- prep: M = edge_anchor @ W1b.T ----
__global__ __launch_bounds__(128) void k_prepM(
    const float* __restrict__ W1, const float* __restrict__ edge_anchor,
    float* __restrict__ M) {
  const int i = threadIdx.x;
  const int a = blockIdx.x;
  float s = 0.f;
  for (int j = 0; j < DIM; ++j)
    s = fmaf(edge_anchor[a * DIM + j], W1[i * 2 * DIM + DIM + j], s);
  M[a * DIM + i] = s;
}

// ---- pack W1 (A-frags, native) and W2 (A-frags with sigma/tau permutation)
// layout: wp[((mat*2+part)*32 + nf*4+ks)*64 + lane], 16B each (8 bf16)
__global__ __launch_bounds__(256) void k_wpack(
    const float* __restrict__ W1, const float* __restrict__ W2,
    uint4* __restrict__ wp) {
  const int mat = blockIdx.x >> 3, nf = blockIdx.x & 7;
  const int ks = threadIdx.x >> 6, lane = threadIdx.x & 63;
  const int g = lane >> 4, r = lane & 15;
  float v[8];
  if (mat == 0) {
    const float* src = W1 + (16 * nf + r) * 256 + 32 * ks + 8 * g;
    float4 a = *(const float4*)src;
    float4 b = *(const float4*)(src + 4);
    v[0] = a.x; v[1] = a.y; v[2] = a.z; v[3] = a.w;
    v[4] = b.x; v[5] = b.y; v[6] = b.z; v[7] = b.w;
  } else {
    // tau = 32*(nf>>1) + 8*(r>>2) + 4*(nf&1) + (r&3)
    // sigma = 32ks + 16*(j>>2) + 4g + (j&3)
    const int trow = 32 * (nf >> 1) + 8 * (r >> 2) + 4 * (nf & 1) + (r & 3);
    const float* src = W2 + trow * 128 + 32 * ks + 4 * g;
    float4 a = *(const float4*)src;         // j=0..3
    float4 b = *(const float4*)(src + 16);  // j=4..7
    v[0] = a.x; v[1] = a.y; v[2] = a.z; v[3] = a.w;
    v[4] = b.x; v[5] = b.y; v[6] = b.z; v[7] = b.w;
  }
  unsigned h[4], l[4];
#pragma unroll
  for (int w = 0; w < 4; ++w) {
    h[w] = pkhi(v[2 * w], v[2 * w + 1]);
    l[w] = pkhi(lof(v[2 * w]), lof(v[2 * w + 1]));
  }
  wp[((mat * 2 + 0) * 32 + nf * 4 + ks) * 64 + lane] =
      make_uint4(h[0], h[1], h[2], h[3]);
  wp[((mat * 2 + 1) * 32 + nf * 4 + ks) * 64 + lane] =
      make_uint4(l[0], l[1], l[2], l[3]);
}

// ---- node pre-pass: att softmax + node_x, and p1/p2 edge projections ----
__global__ __launch_bounds__(256) void k_node(
    const float* __restrict__ x, const float* __restrict__ W_att,
    const float* __restrict__ b_att, const float* __restrict__ node_anchor,
    const float* __restrict__ W_edge, const float* __restrict__ b_edge,
    float* __restrict__ node_x, float* __restrict__ p12) {
  const int wid = threadIdx.x >> 6, lane = threadIdx.x & 63;
  const int d0 = lane << 1;
  float wa0[NA], wa1[NA], we10[NA], we11[NA], we20[NA], we21[NA];
  float na0[NA], na1[NA], ba[NA], be[NA];
#pragma unroll
  for (int a = 0; a < NA; ++a) {
    wa0[a] = W_att[a * DIM + d0];
    wa1[a] = W_att[a * DIM + d0 + 1];
    we10[a] = W_edge[a * 2 * DIM + d0];
    we11[a] = W_edge[a * 2 * DIM + d0 + 1];
    we20[a] = W_edge[a * 2 * DIM + DIM + d0];
    we21[a] = W_edge[a * 2 * DIM + DIM + d0 + 1];
    na0[a] = node_anchor[a * DIM + d0];
    na1[a] = node_anchor[a * DIM + d0 + 1];
    ba[a] = b_att[a];
    be[a] = b_edge[a];
  }
  const int stride = gridDim.x << 2;
  for (int n = (blockIdx.x << 2) + wid; n < NN; n += stride) {
    float2 xv = *(const float2*)(x + (size_t)n * DIM + d0);
    float att[NA], p1[NA], p2[NA];
#pragma unroll
    for (int a = 0; a < NA; ++a) {
      att[a] = wsum(xv.x * wa0[a] + xv.y * wa1[a]) + ba[a];
      p1[a] = wsum(xv.x * we10[a] + xv.y * we11[a]) + be[a];
      p2[a] = wsum(xv.x * we20[a] + xv.y * we21[a]);
    }
    float m = fmaxf(fmaxf(fmaxf(att[0], att[1]), fmaxf(att[2], att[3])), att[4]);
    float s = 0.f;
#pragma unroll
    for (int a = 0; a < NA; ++a) { att[a] = expf(att[a] - m); s += att[a]; }
    float inv = 1.f / s;
    float2 nx = xv;
#pragma unroll
    for (int a = 0; a < NA; ++a) {
      float w = att[a] * inv;
      nx.x = fmaf(w, na0[a], nx.x);
      nx.y = fmaf(w, na1[a], nx.y);
    }
    *(float2*)(node_x + (size_t)n * DIM + d0) = nx;
    if (lane < NA) {
      float v1 = p1[0], v2 = p2[0];
#pragma unroll
      for (int a = 1; a < NA; ++a)
        if (lane == a) { v1 = p1[a]; v2 = p2[a]; }
      p12[(size_t)n * 12 + lane] = v1;
      p12[(size_t)n * 12 + 6 + lane] = v2;
    }
  }
}

__device__ __forceinline__ void edge_b(const float* __restrict__ p12, int src,
                                       int dst, float* __restrict__ b) {
  float4 q1 = *(const float4*)(p12 + (size_t)src * 12);
  float p14 = p12[(size_t)src * 12 + 4];
  float2 r0 = *(const float2*)(p12 + (size_t)dst * 12 + 6);
  float2 r1 = *(const float2*)(p12 + (size_t)dst * 12 + 8);
  float p24 = p12[(size_t)dst * 12 + 10];
  float l[NA] = {q1.x + r0.x, q1.y + r0.y, q1.z + r1.x, q1.w + r1.y,
                 p14 + p24};
#pragma unroll
  for (int a = 0; a < NA; ++a) l[a] = l[a] >= 0.f ? l[a] : 0.01f * l[a];
  float m = fmaxf(fmaxf(fmaxf(l[0], l[1]), fmaxf(l[2], l[3])), l[4]);
  float s = 0.f;
#pragma unroll
  for (int a = 0; a < NA; ++a) { l[a] = expf(l[a] - m); s += l[a]; }
  float inv = 1.f / s;
#pragma unroll
  for (int a = 0; a < NA; ++a) b[a] = l[a] * inv;
}

// ---- fused edge pass: coeff atomics (2 u64/edge: one per endpoint) + ep ----
__global__ __launch_bounds__(256) void k_edge2(
    const int* __restrict__ ei, const float* __restrict__ p12,
    const float* __restrict__ edge_anchor,
    unsigned long long* __restrict__ coeffp, float* __restrict__ ep) {
  __shared__ float bs[4][64][8];
  const int t = threadIdx.x;
  const int w = t >> 6, lane = t & 63;
  const int e = blockIdx.x * 256 + t;
  {
    const int src = ei[e], dst = ei[NE + e];
    float b[NA];
    edge_b(p12, src, dst, b);
    // 4 x 14-bit slots (scale 2^7, q<=128, deg<=127 => sum<16384) + count@56
    unsigned long long q0 = (unsigned)fmaf(b[0], CSCALE3, 0.5f);
    unsigned long long q1 = (unsigned)fmaf(b[1], CSCALE3, 0.5f);
    unsigned long long q2 = (unsigned)fmaf(b[2], CSCALE3, 0.5f);
    unsigned long long q3 = (unsigned)fmaf(b[3], CSCALE3, 0.5f);
    unsigned long long wv =
        q0 | (q1 << 14) | (q2 << 28) | (q3 << 42) | (1ull << 56);
    atomicAdd(coeffp + src, wv);
    atomicAdd(coeffp + dst, wv);
    // wave-private LDS slice: same-wave DS ops are in-order, no barrier
    *(float4*)&bs[w][lane][0] = make_float4(b[0], b[1], b[2], b[3]);
    bs[w][lane][4] = b[4];
  }
  // 2 edges per iter, float4 NT stores
  const int esub = lane >> 5, d0 = (lane & 31) << 2;
  float4 ea4[NA];
#pragma unroll
  for (int a = 0; a < NA; ++a)
    ea4[a] = *(const float4*)(edge_anchor + a * DIM + d0);
  const size_t ebase = (size_t)blockIdx.x * 256 + ((size_t)w << 6);
#pragma unroll 2
  for (int k = 0; k < 32; ++k) {
    const int el = 2 * k + esub;
    float4 c = *(const float4*)&bs[w][el][0];
    float c4 = bs[w][el][4];
    f32x4 v;
#pragma unroll
    for (int i = 0; i < 4; ++i) {
      float s = c.x * ((const float*)&ea4[0])[i];
      s = fmaf(c.y, ((const float*)&ea4[1])[i], s);
      s = fmaf(c.z, ((const float*)&ea4[2])[i], s);
      s = fmaf(c.w, ((const float*)&ea4[3])[i], s);
      s = fmaf(c4, ((const float*)&ea4[4])[i], s);
      v[i] = s;
    }
    __builtin_nontemporal_store(v, (f32x4*)(ep + (ebase + el) * DIM + d0));
  }
}

// ---- ODE: all 5 steps in ONE launch, each seam hard-fenced
// (__syncthreads + sched_barrier(0)) so per-step register pressure equals the
// proven spill-free single-step kernel (r16/r17 validated the seam recipe).
#define WF(MAT, PART, IDX) (*(const short8v*)&wl[MAT][PART][IDX][lane])

#define MFMA3(WH, WO, BH, BL, ACC)                                            \
  ACC = __builtin_amdgcn_mfma_f32_16x16x32_bf16(                              \
      WH, __builtin_bit_cast(short8v, BH), ACC, 0, 0, 0);                     \
  ACC = __builtin_amdgcn_mfma_f32_16x16x32_bf16(                              \
      WH, __builtin_bit_cast(short8v, BL), ACC, 0, 0, 0);                     \
  ACC = __builtin_amdgcn_mfma_f32_16x16x32_bf16(                              \
      WO, __builtin_bit_cast(short8v, BH), ACC, 0, 0, 0);

#define LOADKS(KS, BH, BL)                                                    \
  {                                                                           \
    float4 a = make_float4(0.f, 0.f, 0.f, 0.f), b = a;                        \
    if (ok) {                                                                 \
      const float* p = ev + (size_t)node * DIM + 32 * KS + 8 * g;             \
      a = *(const float4*)p;                                                  \
      b = *(const float4*)(p + 4);                                            \
    }                                                                         \
    BH[0] = pkhi(a.x, a.y); BL[0] = pkhi(lof(a.x), lof(a.y));                 \
    BH[1] = pkhi(a.z, a.w); BL[1] = pkhi(lof(a.z), lof(a.w));                 \
    BH[2] = pkhi(b.x, b.y); BL[2] = pkhi(lof(b.x), lof(b.y));                 \
    BH[3] = pkhi(b.z, b.w); BL[3] = pkhi(lof(b.z), lof(b.w));                 \
  }

// mv1 for one nf: transient aggp init (LDS Ms/b1s), 12 MFMAs in 2 chains,
// relu, pack into Qh/Ql words (compile-time slots).
#define MV1NF(NF, QH, QL, W0)                                                 \
  {                                                                           \
    float4 bb = *(const float4*)&b1s[16 * NF + 4 * g];                        \
    f32x4 acc = {bb.x, bb.y, bb.z, bb.w};                                     \
    {                                                                         \
      float4 mm = *(const float4*)&Ms[0][16 * NF + 4 * g];                    \
      acc[0] = fmaf(c0, mm.x, acc[0]); acc[1] = fmaf(c0, mm.y, acc[1]);       \
      acc[2] = fmaf(c0, mm.z, acc[2]); acc[3] = fmaf(c0, mm.w, acc[3]);       \
    }                                                                         \
    {                                                                         \
      float4 mm = *(const float4*)&Ms[1][16 * NF + 4 * g];                    \
      acc[0] = fmaf(c1, mm.x, acc[0]); acc[1] = fmaf(c1, mm.y, acc[1]);       \
      acc[2] = fmaf(c1, mm.z, acc[2]); acc[3] = fmaf(c1, mm.w, acc[3]);       \
    }                                                                         \
    {                                                                         \
      float4 mm = *(const float4*)&Ms[2][16 * NF + 4 * g];                    \
      acc[0] = fmaf(c2, mm.x, acc[0]); acc[1] = fmaf(c2, mm.y, acc[1]);       \
      acc[2] = fmaf(c2, mm.z, acc[2]); acc[3] = fmaf(c2, mm.w, acc[3]);       \
    }                                                                         \
    {                                                                         \
      float4 mm = *(const float4*)&Ms[3][16 * NF + 4 * g];                    \
      acc[0] = fmaf(c3, mm.x, acc[0]); acc[1] = fmaf(c3, mm.y, acc[1]);       \
      acc[2] = fmaf(c3, mm.z, acc[2]); acc[3] = fmaf(c3, mm.w, acc[3]);       \
    }                                                                         \
    {                                                                         \
      float4 mm = *(const float4*)&Ms[4][16 * NF + 4 * g];                    \
      acc[0] = fmaf(c4, mm.x, acc[0]); acc[1] = fmaf(c4, mm.y, acc[1]);       \
      acc[2] = fmaf(c4, mm.z, acc[2]); acc[3] = fmaf(c4, mm.w, acc[3]);       \
    }                                                                         \
    f32x4 accB = {0.f, 0.f, 0.f, 0.f};                                        \
    { short8v wh = WF(0, 0, NF * 4 + 0), wo = WF(0, 1, NF * 4 + 0);           \
      MFMA3(wh, wo, Bh0, Bl0, acc) }                                          \
    { short8v wh = WF(0, 0, NF * 4 + 1), wo = WF(0, 1, NF * 4 + 1);           \
      MFMA3(wh, wo, Bh1, Bl1, accB) }                                         \
    { short8v wh = WF(0, 0, NF * 4 + 2), wo = WF(0, 1, NF * 4 + 2);           \
      MFMA3(wh, wo, Bh2, Bl2, acc) }                                          \
    { short8v wh = WF(0, 0, NF * 4 + 3), wo = WF(0, 1, NF * 4 + 3);           \
      MFMA3(wh, wo, Bh3, Bl3, accB) }                                         \
    float h0 = fmaxf(acc[0] + accB[0], 0.f);                                  \
    float h1 = fmaxf(acc[1] + accB[1], 0.f);                                  \
    float h2 = fmaxf(acc[2] + accB[2], 0.f);                                  \
    float h3 = fmaxf(acc[3] + accB[3], 0.f);                                  \
    QH[W0] = pkhi(h0, h1);                                                    \
    QH[W0 + 1] = pkhi(h2, h3);                                                \
    QL[W0] = pkhi(lof(h0), lof(h1));                                          \
    QL[W0 + 1] = pkhi(lof(h2), lof(h3));                                      \
  }

// mv2 24-MFMA core for one kq (nf=2kq and 2kq+1), 2 chains each
#define MV2CORE(KQ)                                                           \
  f32x4 a2a = {0.f, 0.f, 0.f, 0.f}, a2aB = a2a;                               \
  { short8v wh = WF(1, 0, (2 * KQ) * 4 + 0), wo = WF(1, 1, (2 * KQ) * 4 + 0); \
    MFMA3(wh, wo, Qh0, Ql0, a2a) }                                            \
  { short8v wh = WF(1, 0, (2 * KQ) * 4 + 1), wo = WF(1, 1, (2 * KQ) * 4 + 1); \
    MFMA3(wh, wo, Qh1, Ql1, a2aB) }                                           \
  { short8v wh = WF(1, 0, (2 * KQ) * 4 + 2), wo = WF(1, 1, (2 * KQ) * 4 + 2); \
    MFMA3(wh, wo, Qh2, Ql2, a2a) }                                            \
  { short8v wh = WF(1, 0, (2 * KQ) * 4 + 3), wo = WF(1, 1, (2 * KQ) * 4 + 3); \
    MFMA3(wh, wo, Qh3, Ql3, a2aB) }                                           \
  f32x4 a2b = {0.f, 0.f, 0.f, 0.f}, a2bB = a2b;                               \
  { short8v wh = WF(1, 0, (2 * KQ + 1) * 4 + 0), wo = WF(1, 1, (2 * KQ + 1) * 4 + 0); \
    MFMA3(wh, wo, Qh0, Ql0, a2b) }                                            \
  { short8v wh = WF(1, 0, (2 * KQ + 1) * 4 + 1), wo = WF(1, 1, (2 * KQ + 1) * 4 + 1); \
    MFMA3(wh, wo, Qh1, Ql1, a2bB) }                                           \
  { short8v wh = WF(1, 0, (2 * KQ + 1) * 4 + 2), wo = WF(1, 1, (2 * KQ + 1) * 4 + 2); \
    MFMA3(wh, wo, Qh2, Ql2, a2b) }                                            \
  { short8v wh = WF(1, 0, (2 * KQ + 1) * 4 + 3), wo = WF(1, 1, (2 * KQ + 1) * 4 + 3); \
    MFMA3(wh, wo, Qh3, Ql3, a2bB) }

// mv2 + store to ev (final step)
#define MV2KQ(KQ, BH, BL)                                                     \
  {                                                                           \
    MV2CORE(KQ)                                                               \
    if (ok) {                                                                 \
      float4 bv0 = *(const float4*)&b2s[32 * KQ + 8 * g];                     \
      float4 bv1 = *(const float4*)&b2s[32 * KQ + 8 * g + 4];                 \
      float4 o0, o1;                                                          \
      o0.x = upk0(BH[0]) + upk0(BL[0]) + fmaf(dt, a2a[0] + a2aB[0], bv0.x);   \
      o0.y = upk1(BH[0]) + upk1(BL[0]) + fmaf(dt, a2a[1] + a2aB[1], bv0.y);   \
      o0.z = upk0(BH[1]) + upk0(BL[1]) + fmaf(dt, a2a[2] + a2aB[2], bv0.z);   \
      o0.w = upk1(BH[1]) + upk1(BL[1]) + fmaf(dt, a2a[3] + a2aB[3], bv0.w);   \
      o1.x = upk0(BH[2]) + upk0(BL[2]) + fmaf(dt, a2b[0] + a2bB[0], bv1.x);   \
      o1.y = upk1(BH[2]) + upk1(BL[2]) + fmaf(dt, a2b[1] + a2bB[1], bv1.y);   \
      o1.z = upk0(BH[3]) + upk0(BL[3]) + fmaf(dt, a2b[2] + a2bB[2], bv1.z);   \
      o1.w = upk1(BH[3]) + upk1(BL[3]) + fmaf(dt, a2b[3] + a2bB[3], bv1.w);   \
      float* p = ev + (size_t)node * DIM + 32 * KQ + 8 * g;                   \
      *(float4*)p = o0;                                                       \
      *(float4*)(p + 4) = o1;                                                 \
    }                                                                         \
  }

// mv2 + in-register update of Bh/Bl (intermediate step; hi+lo split is exact,
// so this is bit-identical to store->reload->repack)
#define MV2KQR(KQ, BH, BL)                                                    \
  {                                                                           \
    MV2CORE(KQ)                                                               \
    float4 bv0 = *(const float4*)&b2s[32 * KQ + 8 * g];                       \
    float4 bv1 = *(const float4*)&b2s[32 * KQ + 8 * g + 4];                   \
    float n0 = upk0(BH[0]) + upk0(BL[0]) + fmaf(dt, a2a[0] + a2aB[0], bv0.x); \
    float n1 = upk1(BH[0]) + upk1(BL[0]) + fmaf(dt, a2a[1] + a2aB[1], bv0.y); \
    float n2 = upk0(BH[1]) + upk0(BL[1]) + fmaf(dt, a2a[2] + a2aB[2], bv0.z); \
    float n3 = upk1(BH[1]) + upk1(BL[1]) + fmaf(dt, a2a[3] + a2aB[3], bv0.w); \
    float n4 = upk0(BH[2]) + upk0(BL[2]) + fmaf(dt, a2b[0] + a2bB[0], bv1.x); \
    float n5 = upk1(BH[2]) + upk1(BL[2]) + fmaf(dt, a2b[1] + a2bB[1], bv1.y); \
    float n6 = upk0(BH[3]) + upk0(BL[3]) + fmaf(dt, a2b[2] + a2bB[2], bv1.z); \
    float n7 = upk1(BH[3]) + upk1(BL[3]) + fmaf(dt, a2b[3] + a2bB[3], bv1.w); \
    BH[0] = pkhi(n0, n1); BL[0] = pkhi(lof(n0), lof(n1));                     \
    BH[1] = pkhi(n2, n3); BL[1] = pkhi(lof(n2), lof(n3));                     \
    BH[2] = pkhi(n4, n5); BL[2] = pkhi(lof(n4), lof(n5));                     \
    BH[3] = pkhi(n6, n7); BL[3] = pkhi(lof(n6), lof(n7));                     \
  }

#define MV1_ALL                                                               \
  MV1NF(0, Qh0, Ql0, 0) MV1NF(1, Qh0, Ql0, 2)                                 \
  MV1NF(2, Qh1, Ql1, 0) MV1NF(3, Qh1, Ql1, 2)                                 \
  MV1NF(4, Qh2, Ql2, 0) MV1NF(5, Qh2, Ql2, 2)                                 \
  MV1NF(6, Qh3, Ql3, 0) MV1NF(7, Qh3, Ql3, 2)

// one intermediate ODE step (in-register EV update)
#define STEP_MID                                                              \
  {                                                                           \
    u32x4 Qh0, Qh1, Qh2, Qh3, Ql0, Ql1, Ql2, Ql3;                             \
    MV1_ALL                                                                   \
    MV2KQR(0, Bh0, Bl0)                                                       \
    MV2KQR(1, Bh1, Bl1)                                                       \
    MV2KQR(2, Bh2, Bl2)                                                       \
    MV2KQR(3, Bh3, Bl3)                                                       \
  }

// seam: memory fence + hard scheduling barrier (nothing crosses)
#define SEAM                                                                  \
  __syncthreads();                                                            \
  __builtin_amdgcn_sched_barrier(0);

#define PROLOGUE                                                              \
  __shared__ uint4 wl[2][2][32][64];                                          \
  __shared__ float b2s[DIM];                                                  \
  __shared__ float b1s[DIM];                                                  \
  __shared__ float Ms[NA][DIM];                                               \
  const int tid = threadIdx.x;                                                \
  {                                                                           \
    uint4* dst = &wl[0][0][0][0];                                             \
    _Pragma("unroll")                                                         \
    for (int i = 0; i < 16; ++i) dst[i * 512 + tid] = wp[i * 512 + tid];      \
  }                                                                           \
  if (tid < DIM) {                                                            \
    b2s[tid] = (1.f / STEPS) * b2[tid];                                       \
    b1s[tid] = b1[tid];                                                       \
  }                                                                           \
  if (tid >= DIM && tid < DIM + NA * DIM / 4) {                               \
    const int q = tid - DIM;                                                  \
    ((float4*)&Ms[0][0])[q] = ((const float4*)M)[q];                          \
  }                                                                           \
  const int wid = tid >> 6, lane = tid & 63;                                  \
  const int g = lane >> 4, r = lane & 15;                                     \
  const int node = blockIdx.x * 128 + wid * 16 + r;                           \
  const bool ok = node < NN;                                                  \
  const float dt = 1.f / STEPS;                                               \
  u32x4 Bh0, Bh1, Bh2, Bh3, Bl0, Bl1, Bl2, Bl3;                               \
  LOADKS(0, Bh0, Bl0)                                                         \
  LOADKS(1, Bh1, Bl1)                                                         \
  LOADKS(2, Bh2, Bl2)                                                         \
  LOADKS(3, Bh3, Bl3)                                                         \
  float c0 = 0.f, c1 = 0.f, c2 = 0.f, c3 = 0.f, c4 = 0.f;                     \
  if (ok) {                                                                   \
    unsigned long long v = coeffp[node];                                      \
    c0 = (float)(unsigned)(v & 0x3FFFu) * CINV3;                              \
    c1 = (float)(unsigned)((v >> 14) & 0x3FFFu) * CINV3;                      \
    c2 = (float)(unsigned)((v >> 28) & 0x3FFFu) * CINV3;                      \
    c3 = (float)(unsigned)((v >> 42) & 0x3FFFu) * CINV3;                      \
    float cnt = (float)(unsigned)(v >> 56);                                   \
    c4 = cnt - (c0 + c1 + c2 + c3);                                           \
  }                                                                           \
  __syncthreads();

// all 5 ODE steps, 4 fenced seams (r17 config: 512 threads, 8 waves/block)
__global__ __launch_bounds__(512) void k_step5(
    const unsigned long long* __restrict__ coeffp, const float* __restrict__ M,
    const uint4* __restrict__ wp, const float* __restrict__ b1,
    const float* __restrict__ b2, float* __restrict__ ev) {
  PROLOGUE
  STEP_MID
  SEAM
  STEP_MID
  SEAM
  STEP_MID
  SEAM
  STEP_MID
  SEAM
  {
    u32x4 Qh0, Qh1, Qh2, Qh3, Ql0, Ql1, Ql2, Ql3;
    MV1_ALL
    MV2KQ(0, Bh0, Bl0)
    MV2KQ(1, Bh1, Bl1)
    MV2KQ(2, Bh2, Bl2)
    MV2KQ(3, Bh3, Bl3)
  }
}

extern "C" void kernel_launch(void* const* d_in, const int* in_sizes, int n_in,
                              void* d_out, int out_size, void* d_ws,
                              size_t ws_size, hipStream_t stream) {
  const float* x = (const float*)d_in[0];
  const int* ei = (const int*)d_in[1];
  const float* node_anchor = (const float*)d_in[2];
  const float* W_att = (const float*)d_in[3];
  const float* b_att = (const float*)d_in[4];
  const float* edge_anchor = (const float*)d_in[5];
  const float* W_edge = (const float*)d_in[6];
  const float* b_edge = (const float*)d_in[7];
  const float* W1 = (const float*)d_in[8];
  const float* b1 = (const float*)d_in[9];
  const float* W2 = (const float*)d_in[10];
  const float* b2 = (const float*)d_in[11];

  float* out = (float*)d_out;
  float* ev = out;                     // N*DIM (node_x staged here, then ev)
  float* ep = out + (size_t)NN * DIM;  // E*DIM edge_prompt

  char* ws = (char*)d_ws;
  float* p12 = (float*)(ws);  // N*12 floats = 4.8 MB
  unsigned long long* coeffp =
      (unsigned long long*)(ws + 4800000);   // N u64 = 0.8 MB
  float* Mm = (float*)(ws + 5600000);        // 5*128 floats
  uint4* wpack = (uint4*)(ws + 5602560);     // 128 KB packed W frags

  hipMemsetAsync(coeffp, 0, (size_t)NN * sizeof(unsigned long long), stream);
  k_prepM<<<NA, DIM, 0, stream>>>(W1, edge_anchor, Mm);
  k_wpack<<<16, 256, 0, stream>>>(W1, W2, wpack);
  k_node<<<2048, 256, 0, stream>>>(x, W_att, b_att, node_anchor, W_edge, b_edge,
                                   ev, p12);
  k_edge2<<<NE / 256, 256, 0, stream>>>(ei, p12, edge_anchor, coeffp, ep);
  k_step5<<<(NN + 127) / 128, 512, 0, stream>>>(coeffp, Mm, wpack, b1, b2, ev);
}